// Round 13
// baseline (267.139 us; speedup 1.0000x reference)
//
#include <hip/hip_runtime.h>
#include <math.h>

#define KQ   32768
#define CC   100
#define BB   1024
#define DD   128
#define NTOT (BB + KQ)        // 33792
#define CB_CENT 1056
#define NCB  1060             // 32-row blocks in X2
#define NHIST 33              // histogram partial blocks
#define NCG2 132              // branch-2 col groups (8 cb each)
#define CG_SUP 141            // sup group id
#define NSL  141              // partial-sum slices (132 b2 + 9 b1)
#define NACT 1136             // active gemm blocks (cg 0..141, 8 rt each)

#define INV_T  14.285714285714286f
#define K2E    20.609929f     // INV_T * log2(e)
#define ALPHA  0.05f
#define EPSV   1e-12f

typedef __attribute__((ext_vector_type(8)))  short          short8;
typedef __attribute__((ext_vector_type(8)))  unsigned short ushort8;
typedef __attribute__((ext_vector_type(16))) float          float16;

__device__ __forceinline__ unsigned short f2bf_rne(float f) {
    unsigned int u = __float_as_uint(f);
    return (unsigned short)((u + 0x7FFFu + ((u >> 16) & 1u)) >> 16);
}

// X2 layout per 32-row block cb (8192 B): [ks 0..7][lane 0..63][16 B]
// element (row r, k): cb=r>>5, ks=k>>4, lane=(r&31)+32*((k>>3)&1), j=k&7
// == 32x32x16 MFMA A/B operand layout (verified R2-R12).

// ---------------- prep: convert+tile + partial histograms + ticket zero ----------------
__global__ __launch_bounds__(256) void prep_k(const float* __restrict__ feats,
                                              const float* __restrict__ centers,
                                              const int* __restrict__ labels,
                                              unsigned short* __restrict__ X2,
                                              int* __restrict__ cntP,
                                              int* __restrict__ cntB,
                                              unsigned int* __restrict__ ticket) {
    const int b = blockIdx.x, t = threadIdx.x;
    if (b >= NCB) {  // histogram partials: each block owns its own 128-int slice
        const int h = b - NCB;
        __shared__ int hA[CC], hB[CC];
        if (t < CC) { hA[t] = 0; hB[t] = 0; }
        __syncthreads();
        const int base = h * 1024;
#pragma unroll
        for (int q = 0; q < 4; ++q) {
            int l = labels[base + q * 256 + t];
            atomicAdd(&hA[l], 1);
            if (h == 0) atomicAdd(&hB[l], 1);   // batch rows are exactly block 0's range
        }
        __syncthreads();
        if (t < 128) {
            cntP[h * 128 + t] = (t < CC) ? hA[t] : 0;
            if (h == 0) cntB[t] = (t < CC) ? hB[t] : 0;
        }
        if (h == 0 && t == 128) *ticket = 0u;
        return;
    }
    __shared__ unsigned short sm[8 * 66 * 8];   // stride-66 slots
    const int rl = t >> 3, c8 = t & 7;
    const int r = b * 32 + rl;
    const float* src;
    if (r < NTOT)            src = &feats[(size_t)r * DD];
    else if (r < NTOT + CC)  src = &centers[(size_t)(r - NTOT) * DD];
    else                     src = nullptr;
#pragma unroll
    for (int s = 0; s < 2; ++s) {
        const int c8p = c8 + 8 * s;
        float v[8];
        if (src) {
            const float4* p = (const float4*)(src + c8p * 8);
            float4 q0 = p[0], q1 = p[1];
            v[0]=q0.x; v[1]=q0.y; v[2]=q0.z; v[3]=q0.w;
            v[4]=q1.x; v[5]=q1.y; v[6]=q1.z; v[7]=q1.w;
        } else {
#pragma unroll
            for (int j = 0; j < 8; ++j) v[j] = 0.f;
        }
        ushort8 H;
#pragma unroll
        for (int m = 0; m < 8; ++m) H[m] = f2bf_rne(v[m]);
        const int ks = c8p >> 1, lh = c8p & 1;
        *(ushort8*)&sm[(ks * 66 + rl + 32 * lh) * 8] = H;
    }
    __syncthreads();
    ushort8* dst = (ushort8*)((char*)X2 + (size_t)b * 8192);
#pragma unroll
    for (int j = 0; j < 2; ++j) {
        const int idx = j * 256 + t;
        const int ks = idx >> 6, ln = idx & 63;
        dst[idx] = *(const ushort8*)&sm[(ks * 66 + ln) * 8];
    }
}

// ---------------- epilogue for one 32x32 tile ----------------
__device__ __forceinline__ void epi_tile(
    const float16& acc, int cb, int lc, float rn, float drm, bool checkDiag,
    int half, int ln, int growbase, const int* rlab, float* sS, float* sN)
{
    const int ccol = cb * 32 + ln;
#pragma unroll
    for (int reg = 0; reg < 16; ++reg) {
        int ro = (reg & 3) + 8 * (reg >> 2) + 4 * half;
        float a  = acc[reg];
        float mf = (lc == rlab[reg]) ? 1.f : 0.f;
        float wgt = fmaf(mf, drm, rn);
        if (checkDiag) {                 // wave-uniform
            bool d = (ccol == growbase + ro);
            wgt = d ? 0.f : wgt;
            mf  = d ? 0.f : mf;
        }
        float e = exp2f(fmaf(a, K2E, -K2E));
        sS[reg] = fmaf(e, wgt, sS[reg]);
        sN[reg] = fmaf(mf, a, sN[reg]);  // un-scaled dot; *INV_T at finalize
    }
}

// ---------------- dual-stream pair of 32x32 tiles ----------------
__device__ __forceinline__ void pair_tiles(
    const char* Xb, int cb0, int cb1,
    int lc0, float rn0, float drm0, bool dg0,
    int lc1, float rn1, float drm1, bool dg1,
    int lane, int half, int ln, int growbase,
    const short8* Ah, const int* rlab, float* sS, float* sN)
{
    const size_t b0 = (size_t)cb0 * 8192 + (size_t)lane * 16;
    const size_t b1 = (size_t)cb1 * 8192 + (size_t)lane * 16;
    float16 a0, a1;
#pragma unroll
    for (int reg = 0; reg < 16; ++reg) { a0[reg] = 0.f; a1[reg] = 0.f; }
#pragma unroll
    for (int ks = 0; ks < 8; ++ks) {
        short8 B0 = *(const short8*)(Xb + b0 + (size_t)ks * 1024);
        short8 B1 = *(const short8*)(Xb + b1 + (size_t)ks * 1024);
        a0 = __builtin_amdgcn_mfma_f32_32x32x16_bf16(Ah[ks], B0, a0, 0, 0, 0);
        a1 = __builtin_amdgcn_mfma_f32_32x32x16_bf16(Ah[ks], B1, a1, 0, 0, 0);
    }
    epi_tile(a0, cb0, lc0, rn0, drm0, dg0, half, ln, growbase, rlab, sS, sN);
    epi_tile(a1, cb1, lc1, rn1, drm1, dg1, half, ln, growbase, rlab, sS, sN);
}

// ---------------- fused GEMM + sup-sums + ticket-gated finalize ----------------
// grid 1152 = 8 xcd * 8 rt * 18 ci; cg = xcd + 8*ci.
// cg<132: branch2 (8 cb). 132..140: branch1 (4 cb). 141: sup sums. >141: idle.
__global__ __launch_bounds__(256) void gemm_k(
    const unsigned short* __restrict__ X2, const int* __restrict__ labels,
    const int* __restrict__ cntP, const int* __restrict__ cntB,
    const float* __restrict__ sup,
    float* __restrict__ pS, float* __restrict__ pN,
    float* __restrict__ supS, float* __restrict__ supLi,
    unsigned int* __restrict__ ticket, float* __restrict__ out) {
    const int b = blockIdx.x;
    const int xcd = b & 7, l = b >> 3;
    const int rt = l & 7, ci = l >> 3;
    const int cg = xcd + 8 * ci;
    if (cg > CG_SUP) return;

    const int tid = threadIdx.x;
    const int lane = tid & 63, w = tid >> 6;
    const int half = lane >> 5, ln = lane & 31;
    const char* Xb = (const char*)X2;

    // block-local weight tables from histogram partials
    __shared__ float cntAF[128], rnA[128], drmA[128], rn1S[128], drm1S[128];
    if (tid < 128) {
        int s = 0;
#pragma unroll
        for (int h = 0; h < NHIST; ++h) s += cntP[h * 128 + tid];
        float cf = (float)s;
        cntAF[tid] = cf;
        rnA[tid] = (s > 0) ? __builtin_amdgcn_rcpf(cf) : 0.f;
        drmA[tid] = (s > 0) ? (__builtin_amdgcn_rcpf(cf - ALPHA) - rnA[tid]) : 0.f;
        int sb = cntB[tid];
        float c1 = (float)(sb + 1);
        float rn1 = __builtin_amdgcn_rcpf(c1);
        rn1S[tid] = rn1;
        drm1S[tid] = __builtin_amdgcn_rcpf(fmaxf(c1 - 1.f, 1.f)) - rn1;
    }
    __syncthreads();

    if (cg == CG_SUP) {  // sup-logits exp-sums (lane = class), wave = 32 rows, 4-row batches
        const int g = rt * 4 + w;
        const int c0 = lane, c1 = lane + 64;
        float n0 = cntAF[c0];
        float rA0 = __builtin_amdgcn_rcpf(n0);
        float rAm0 = __builtin_amdgcn_rcpf(fmaxf(n0 - 1.f, 1.f));
        float rA1 = 0.f, rAm1 = 0.f;
        if (lane < 36) {
            float n1 = cntAF[c1];
            rA1 = __builtin_amdgcn_rcpf(n1);
            rAm1 = __builtin_amdgcn_rcpf(fmaxf(n1 - 1.f, 1.f));
        }
        for (int rq = 0; rq < 8; ++rq) {
            float v0[4], v1[4];
            int li[4];
#pragma unroll
            for (int k = 0; k < 4; ++k) {   // batch loads for MLP
                int row = g * 32 + rq * 4 + k;
                li[k] = labels[row];
                const float* srow = &sup[(size_t)row * CC];
                v0[k] = srow[c0];
                v1[k] = (lane < 36) ? srow[c1] : 0.f;
            }
#pragma unroll
            for (int k = 0; k < 4; ++k) {
                int row = g * 32 + rq * 4 + k;
                float s = __expf(v0[k] - INV_T) * ((c0 == li[k]) ? rAm0 : rA0);
                float liv = (c0 == li[k]) ? v0[k] : 0.f;
                if (lane < 36) {
                    s += __expf(v1[k] - INV_T) * ((c1 == li[k]) ? rAm1 : rA1);
                    liv += (c1 == li[k]) ? v1[k] : 0.f;
                }
#pragma unroll
                for (int off = 1; off < 64; off <<= 1) {
                    s += __shfl_xor(s, off, 64);
                    liv += __shfl_xor(liv, off, 64);
                }
                if (lane == 0) { supS[row] = s; supLi[row] = liv; }
            }
        }
    } else {
        const int rb = rt * 4 + w;
        const int growbase = rt * 128 + w * 32;
        short8 Ah[8];
        {
            size_t abase = (size_t)rb * 8192 + (size_t)lane * 16;
#pragma unroll
            for (int ks = 0; ks < 8; ++ks)
                Ah[ks] = *(const short8*)(Xb + abase + (size_t)ks * 1024);
        }
        int rlab[16];
#pragma unroll
        for (int reg = 0; reg < 16; ++reg) {
            int ro = (reg & 3) + 8 * (reg >> 2) + 4 * half;
            rlab[reg] = labels[growbase + ro];
        }
        float sS[16], sN[16];
#pragma unroll
        for (int reg = 0; reg < 16; ++reg) { sS[reg] = 0.f; sN[reg] = 0.f; }

        const bool isB2 = (cg < NCG2);
        const int t1 = cg - NCG2;
        if (isB2) {
#pragma unroll
            for (int p = 0; p < 4; ++p) {
                const int cb0 = cg * 8 + 2 * p, cb1 = cb0 + 1;
                int lc0 = labels[cb0 * 32 + ln];
                int lc1 = labels[cb1 * 32 + ln];
                pair_tiles(Xb, cb0, cb1, lc0, rnA[lc0], drmA[lc0], cb0 == rb,
                           lc1, rnA[lc1], drmA[lc1], cb1 == rb,
                           lane, half, ln, growbase, Ah, rlab, sS, sN);
            }
        } else {
            const bool isBatch = (t1 < 8);
#pragma unroll
            for (int p = 0; p < 2; ++p) {
                int cb0, cb1, lc0, lc1;
                if (isBatch) {
                    cb0 = t1 * 4 + 2 * p; cb1 = cb0 + 1;
                    lc0 = labels[cb0 * 32 + ln];
                    lc1 = labels[cb1 * 32 + ln];
                } else {
                    cb0 = CB_CENT + 2 * p; cb1 = cb0 + 1;
                    int q0 = cb0 * 32 + ln - NTOT, q1 = cb1 * 32 + ln - NTOT;
                    lc0 = (q0 < CC) ? q0 : -1;
                    lc1 = (q1 < CC) ? q1 : -1;
                }
                float rn0 = (lc0 >= 0) ? rn1S[lc0] : 0.f;
                float drm0 = (lc0 >= 0) ? drm1S[lc0] : 0.f;
                float rn1 = (lc1 >= 0) ? rn1S[lc1] : 0.f;
                float drm1 = (lc1 >= 0) ? drm1S[lc1] : 0.f;
                pair_tiles(Xb, cb0, cb1, lc0, rn0, drm0, isBatch && (cb0 == rb),
                           lc1, rn1, drm1, isBatch && (cb1 == rb),
                           lane, half, ln, growbase, Ah, rlab, sS, sN);
            }
        }
        const int slice = isB2 ? cg : (NCG2 + t1);
#pragma unroll
        for (int reg = 0; reg < 16; ++reg) {
            float a = sS[reg], c = sN[reg];
#pragma unroll
            for (int off = 1; off < 32; off <<= 1) {
                a += __shfl_xor(a, off, 64);
                c += __shfl_xor(c, off, 64);
            }
            if (ln == 0) {
                int ro = (reg & 3) + 8 * (reg >> 2) + 4 * half;
                int grow = growbase + ro;
                pS[(size_t)slice * BB + grow] = a;
                pN[(size_t)slice * BB + grow] = c;
            }
        }
    }

    // ---------------- ticket: last active block finalizes (R4/R5-proven pattern) ----------
    __syncthreads();
    __threadfence();
    __shared__ unsigned int lastFlag;
    if (tid == 0) {
        unsigned int old = __hip_atomic_fetch_add(ticket, 1u, __ATOMIC_ACQ_REL,
                                                  __HIP_MEMORY_SCOPE_AGENT);
        lastFlag = (old == NACT - 1) ? 1u : 0u;
    }
    __syncthreads();
    if (!lastFlag) return;
    __threadfence();

    float lsum = 0.f;
#pragma unroll
    for (int q = 0; q < 4; ++q) {
        const int row = q * 256 + tid;
        const int li = labels[row];
        float S2 = supS[row], N2 = 0.f;
#pragma unroll 4
        for (int c = 0; c < NCG2; ++c) {
            S2 += pS[(size_t)c * BB + row];
            N2 += pN[(size_t)c * BB + row];
        }
        float S1 = 0.f, N1v = 0.f;
#pragma unroll
        for (int c = NCG2; c < NSL; ++c) {
            S1 += pS[(size_t)c * BB + row];
            N1v += pN[(size_t)c * BB + row];
        }
        N2 *= INV_T; N1v *= INV_T;
        float sli = supLi[row];
        float cA = cntAF[li];
        float msum2 = fmaf(ALPHA, cA - 1.f, 1.f);
        float loss2 = -(fmaf(ALPHA, N2, sli) / msum2 - INV_T - logf(S2 + EPSV));
        float cb1 = cntAF[li] - 0.f;  (void)cb1;
        float loss1 = -(N1v / (float)cntB[li] - INV_T - logf(S1 + EPSV));
        lsum += loss1 + loss2;
    }
    __shared__ float rbuf[4];
#pragma unroll
    for (int off = 1; off < 64; off <<= 1) lsum += __shfl_xor(lsum, off, 64);
    if (lane == 0) rbuf[w] = lsum;
    __syncthreads();
    if (tid == 0) out[0] = (rbuf[0] + rbuf[1] + rbuf[2] + rbuf[3]) / (float)BB;
}

extern "C" void kernel_launch(void* const* d_in, const int* in_sizes, int n_in,
                              void* d_out, int out_size, void* d_ws, size_t ws_size,
                              hipStream_t stream) {
    const float* feats   = (const float*)d_in[0];
    const float* sup     = (const float*)d_in[1];
    const float* centers = (const float*)d_in[2];
    const int*   labels  = (const int*)d_in[3];
    float* out = (float*)d_out;
    char*  wsb = (char*)d_ws;

    const size_t X2_BYTES = (size_t)NCB * 8192;         // 8,683,520
    unsigned short* X2 = (unsigned short*)wsb;
    char* base2 = wsb + X2_BYTES;
    int* cntP = (int*)base2;                            // 33*128 ints
    int* cntB = cntP + NHIST * 128;                     // 128 ints
    unsigned int* ticket = (unsigned int*)(cntB + 128); // 1 (+pad 127)
    float* pS = (float*)(ticket + 128);                 // 141*1024
    float* pN = pS + (size_t)NSL * BB;                  // 141*1024
    float* supS  = pN + (size_t)NSL * BB;               // 1024
    float* supLi = supS + BB;                           // 1024

    // 2 nodes; every workspace word written before read (ticket zeroed by prep)
    prep_k<<<NCB + NHIST, 256, 0, stream>>>(feats, centers, labels, X2, cntP, cntB, ticket);
    gemm_k<<<8 * 8 * 18, 256, 0, stream>>>(X2, labels, cntP, cntB, sup,
                                           pS, pN, supS, supLi, ticket, out);
}

// Round 15
// 136.285 us; speedup vs baseline: 1.9601x; 1.9601x over previous
//
#include <hip/hip_runtime.h>
#include <math.h>

#define KQ   32768
#define CC   100
#define BB   1024
#define DD   128
#define NTOT (BB + KQ)        // 33792
#define CB_CENT 1056
#define NCB  1060             // 32-row blocks in X2
#define NPB  530              // prep blocks (2 cb each)
#define NHIST 33              // histogram partial blocks
#define NCG2 132              // branch-2 col groups (8 cb each)
#define CG_SUP 141            // sup group id
#define NSL  141              // partial-sum slices (132 b2 + 9 b1)

#define INV_T  14.285714285714286f
#define K2E    20.609929f     // INV_T * log2(e)
#define ALPHA  0.05f
#define EPSV   1e-12f

typedef __attribute__((ext_vector_type(8)))  short          short8;
typedef __attribute__((ext_vector_type(8)))  unsigned short ushort8;
typedef __attribute__((ext_vector_type(16))) float          float16;

__device__ __forceinline__ unsigned short f2bf_rne(float f) {
    unsigned int u = __float_as_uint(f);
    return (unsigned short)((u + 0x7FFFu + ((u >> 16) & 1u)) >> 16);
}

// X2 layout per 32-row block cb (8192 B): [ks 0..7][lane 0..63][16 B]
// element (row r, k): cb=r>>5, ks=k>>4, lane=(r&31)+32*((k>>3)&1), j=k&7
// == 32x32x16 MFMA A/B operand layout (verified R2-R13).
// HARD RULES: no device-scope fences/tickets in hot kernel (R13);
// never plain-store into a cross-block atomic accumulation target (R14).

// ---------------- prep: convert+tile (2 cb/block) + partial histograms ----------------
__global__ __launch_bounds__(256) void prep_k(const float* __restrict__ feats,
                                              const float* __restrict__ centers,
                                              const int* __restrict__ labels,
                                              unsigned short* __restrict__ X2,
                                              int* __restrict__ cntP,
                                              int* __restrict__ cntB) {
    const int b = blockIdx.x, t = threadIdx.x;
    if (b >= NPB) {  // histogram partials: each block owns its own 128-int slice
        const int h = b - NPB;
        __shared__ int hA[CC], hB[CC];
        if (t < CC) { hA[t] = 0; hB[t] = 0; }
        __syncthreads();
        const int base = h * 1024;
#pragma unroll
        for (int q = 0; q < 4; ++q) {
            int l = labels[base + q * 256 + t];
            atomicAdd(&hA[l], 1);
            if (h == 0) atomicAdd(&hB[l], 1);   // batch rows are exactly block 0's range
        }
        __syncthreads();
        if (t < 128) {
            cntP[h * 128 + t] = (t < CC) ? hA[t] : 0;
            if (h == 0) cntB[t] = (t < CC) ? hB[t] : 0;
        }
        return;
    }
    __shared__ unsigned short sm[8 * 66 * 8];   // stride-66 slots, reused per cb
    const int rl = t >> 3, c8 = t & 7;
#pragma unroll
    for (int cbi = 0; cbi < 2; ++cbi) {
        const int cb = b * 2 + cbi;
        const int r = cb * 32 + rl;
        const float* src;
        if (r < NTOT)            src = &feats[(size_t)r * DD];
        else if (r < NTOT + CC)  src = &centers[(size_t)(r - NTOT) * DD];
        else                     src = nullptr;
        if (cbi) __syncthreads();
#pragma unroll
        for (int s = 0; s < 2; ++s) {
            const int c8p = c8 + 8 * s;
            float v[8];
            if (src) {
                const float4* p = (const float4*)(src + c8p * 8);
                float4 q0 = p[0], q1 = p[1];
                v[0]=q0.x; v[1]=q0.y; v[2]=q0.z; v[3]=q0.w;
                v[4]=q1.x; v[5]=q1.y; v[6]=q1.z; v[7]=q1.w;
            } else {
#pragma unroll
                for (int j = 0; j < 8; ++j) v[j] = 0.f;
            }
            ushort8 H;
#pragma unroll
            for (int m = 0; m < 8; ++m) H[m] = f2bf_rne(v[m]);
            const int ks = c8p >> 1, lh = c8p & 1;
            *(ushort8*)&sm[(ks * 66 + rl + 32 * lh) * 8] = H;
        }
        __syncthreads();
        ushort8* dst = (ushort8*)((char*)X2 + (size_t)cb * 8192);
#pragma unroll
        for (int j = 0; j < 2; ++j) {
            const int idx = j * 256 + t;
            const int ks = idx >> 6, ln = idx & 63;
            dst[idx] = *(const ushort8*)&sm[(ks * 66 + ln) * 8];
        }
    }
}

// ---------------- epilogue for one 32x32 tile ----------------
__device__ __forceinline__ void epi_tile(
    const float16& acc, int cb, int lc, float rn, float drm, bool checkDiag,
    int half, int ln, int growbase, const int* rlab, float* sS, float* sN)
{
    const int ccol = cb * 32 + ln;
#pragma unroll
    for (int reg = 0; reg < 16; ++reg) {
        int ro = (reg & 3) + 8 * (reg >> 2) + 4 * half;
        float a  = acc[reg];
        float mf = (lc == rlab[reg]) ? 1.f : 0.f;
        float wgt = fmaf(mf, drm, rn);
        if (checkDiag) {                 // wave-uniform
            bool d = (ccol == growbase + ro);
            wgt = d ? 0.f : wgt;
            mf  = d ? 0.f : mf;
        }
        float e = exp2f(fmaf(a, K2E, -K2E));
        sS[reg] = fmaf(e, wgt, sS[reg]);
        sN[reg] = fmaf(mf, a, sN[reg]);  // un-scaled dot; *INV_T at finalize
    }
}

// ---------------- dual-stream pair of 32x32 tiles ----------------
__device__ __forceinline__ void pair_tiles(
    const char* Xb, int cb0, int cb1,
    int lc0, float rn0, float drm0, bool dg0,
    int lc1, float rn1, float drm1, bool dg1,
    int lane, int half, int ln, int growbase,
    const short8* Ah, const int* rlab, float* sS, float* sN)
{
    const size_t b0 = (size_t)cb0 * 8192 + (size_t)lane * 16;
    const size_t b1 = (size_t)cb1 * 8192 + (size_t)lane * 16;
    float16 a0, a1;
#pragma unroll
    for (int reg = 0; reg < 16; ++reg) { a0[reg] = 0.f; a1[reg] = 0.f; }
#pragma unroll
    for (int ks = 0; ks < 8; ++ks) {
        short8 B0 = *(const short8*)(Xb + b0 + (size_t)ks * 1024);
        short8 B1 = *(const short8*)(Xb + b1 + (size_t)ks * 1024);
        a0 = __builtin_amdgcn_mfma_f32_32x32x16_bf16(Ah[ks], B0, a0, 0, 0, 0);
        a1 = __builtin_amdgcn_mfma_f32_32x32x16_bf16(Ah[ks], B1, a1, 0, 0, 0);
    }
    epi_tile(a0, cb0, lc0, rn0, drm0, dg0, half, ln, growbase, rlab, sS, sN);
    epi_tile(a1, cb1, lc1, rn1, drm1, dg1, half, ln, growbase, rlab, sS, sN);
}

// ---------------- fused GEMM (b2 + b1) + sup-sums; LDS weight table; store epilogue ----------
// grid 1152 = 8 xcd * 8 rt * 18 ci; cg = xcd + 8*ci.
// cg<132: branch2 (8 cb). 132..140: branch1 (4 cb). 141: sup sums. >141: idle.
__global__ __launch_bounds__(256) void gemm_k(
    const unsigned short* __restrict__ X2, const int* __restrict__ labels,
    const int* __restrict__ cntP, const int* __restrict__ cntB,
    const float* __restrict__ sup,
    float* __restrict__ pS, float* __restrict__ pN,
    float* __restrict__ supS, float* __restrict__ supLi) {
    const int b = blockIdx.x;
    const int xcd = b & 7, l = b >> 3;
    const int rt = l & 7, ci = l >> 3;
    const int cg = xcd + 8 * ci;
    if (cg > CG_SUP) return;

    const int tid = threadIdx.x;
    const int lane = tid & 63, w = tid >> 6;
    const int half = lane >> 5, ln = lane & 31;
    const char* Xb = (const char*)X2;

    // block-local weight tables from histogram partials (no cross-block ordering)
    __shared__ float cntAF[128], rnA[128], drmA[128], rn1S[128], drm1S[128];
    if (tid < 128) {
        int s = 0;
#pragma unroll
        for (int h = 0; h < NHIST; ++h) s += cntP[h * 128 + tid];
        float cf = (float)s;
        cntAF[tid] = cf;
        rnA[tid] = (s > 0) ? __builtin_amdgcn_rcpf(cf) : 0.f;
        drmA[tid] = (s > 0) ? (__builtin_amdgcn_rcpf(cf - ALPHA) - rnA[tid]) : 0.f;
        int sb = cntB[tid];
        float c1 = (float)(sb + 1);
        float rn1 = __builtin_amdgcn_rcpf(c1);
        rn1S[tid] = rn1;
        drm1S[tid] = __builtin_amdgcn_rcpf(fmaxf(c1 - 1.f, 1.f)) - rn1;
    }
    __syncthreads();

    if (cg == CG_SUP) {  // sup-logits exp-sums, coalesced (lane = class), wave = 32 rows
        const int g = rt * 4 + w;
        const int c0 = lane, c1 = lane + 64;
        float n0 = cntAF[c0];
        float rA0 = __builtin_amdgcn_rcpf(n0);
        float rAm0 = __builtin_amdgcn_rcpf(fmaxf(n0 - 1.f, 1.f));
        float rA1 = 0.f, rAm1 = 0.f;
        if (lane < 36) {
            float n1 = cntAF[c1];
            rA1 = __builtin_amdgcn_rcpf(n1);
            rAm1 = __builtin_amdgcn_rcpf(fmaxf(n1 - 1.f, 1.f));
        }
        for (int rr = 0; rr < 32; ++rr) {
            int row = g * 32 + rr;
            int li = labels[row];
            const float* srow = &sup[(size_t)row * CC];
            float v0 = srow[c0];
            float s = __expf(v0 - INV_T) * ((c0 == li) ? rAm0 : rA0);
            float liv = (c0 == li) ? v0 : 0.f;
            if (lane < 36) {
                float v1 = srow[c1];
                s += __expf(v1 - INV_T) * ((c1 == li) ? rAm1 : rA1);
                liv += (c1 == li) ? v1 : 0.f;
            }
#pragma unroll
            for (int off = 1; off < 64; off <<= 1) {
                s += __shfl_xor(s, off, 64);
                liv += __shfl_xor(liv, off, 64);
            }
            if (lane == 0) { supS[row] = s; supLi[row] = liv; }
        }
        return;
    }

    const int rb = rt * 4 + w;
    const int growbase = rt * 128 + w * 32;
    short8 Ah[8];
    {
        size_t abase = (size_t)rb * 8192 + (size_t)lane * 16;
#pragma unroll
        for (int ks = 0; ks < 8; ++ks)
            Ah[ks] = *(const short8*)(Xb + abase + (size_t)ks * 1024);
    }
    int rlab[16];
#pragma unroll
    for (int reg = 0; reg < 16; ++reg) {
        int ro = (reg & 3) + 8 * (reg >> 2) + 4 * half;
        rlab[reg] = labels[growbase + ro];
    }
    float sS[16], sN[16];
#pragma unroll
    for (int reg = 0; reg < 16; ++reg) { sS[reg] = 0.f; sN[reg] = 0.f; }

    const bool isB2 = (cg < NCG2);
    const int t1 = cg - NCG2;
    if (isB2) {
#pragma unroll
        for (int p = 0; p < 4; ++p) {
            const int cb0 = cg * 8 + 2 * p, cb1 = cb0 + 1;
            int lc0 = labels[cb0 * 32 + ln];
            int lc1 = labels[cb1 * 32 + ln];
            pair_tiles(Xb, cb0, cb1, lc0, rnA[lc0], drmA[lc0], cb0 == rb,
                       lc1, rnA[lc1], drmA[lc1], cb1 == rb,
                       lane, half, ln, growbase, Ah, rlab, sS, sN);
        }
    } else {
        const bool isBatch = (t1 < 8);
#pragma unroll
        for (int p = 0; p < 2; ++p) {
            int cb0, cb1, lc0, lc1;
            if (isBatch) {
                cb0 = t1 * 4 + 2 * p; cb1 = cb0 + 1;
                lc0 = labels[cb0 * 32 + ln];
                lc1 = labels[cb1 * 32 + ln];
            } else {
                cb0 = CB_CENT + 2 * p; cb1 = cb0 + 1;
                int q0 = cb0 * 32 + ln - NTOT, q1 = cb1 * 32 + ln - NTOT;
                lc0 = (q0 < CC) ? q0 : -1;
                lc1 = (q1 < CC) ? q1 : -1;
            }
            float rn0 = (lc0 >= 0) ? rn1S[lc0] : 0.f;
            float drm0 = (lc0 >= 0) ? drm1S[lc0] : 0.f;
            float rn1 = (lc1 >= 0) ? rn1S[lc1] : 0.f;
            float drm1 = (lc1 >= 0) ? drm1S[lc1] : 0.f;
            pair_tiles(Xb, cb0, cb1, lc0, rn0, drm0, isBatch && (cb0 == rb),
                       lc1, rn1, drm1, isBatch && (cb1 == rb),
                       lane, half, ln, growbase, Ah, rlab, sS, sN);
        }
    }
    const int slice = isB2 ? cg : (NCG2 + t1);
#pragma unroll
    for (int reg = 0; reg < 16; ++reg) {
        float a = sS[reg], c = sN[reg];
#pragma unroll
        for (int off = 1; off < 32; off <<= 1) {
            a += __shfl_xor(a, off, 64);
            c += __shfl_xor(c, off, 64);
        }
        if (ln == 0) {
            int ro = (reg & 3) + 8 * (reg >> 2) + 4 * half;
            int grow = growbase + ro;
            pS[(size_t)slice * BB + grow] = a;
            pN[(size_t)slice * BB + grow] = c;
        }
    }
}

// ---------------- finalize: 8 blocks x 128 threads ----------------
__global__ __launch_bounds__(128) void finalize_k(
    const int* __restrict__ labels,
    const int* __restrict__ cntP, const int* __restrict__ cntB,
    const float* __restrict__ pS, const float* __restrict__ pN,
    const float* __restrict__ supS, const float* __restrict__ supLi,
    float* __restrict__ out) {
    const int t = threadIdx.x;
    const int row = blockIdx.x * 128 + t;
    __shared__ float cntA[128];
    if (t < 128) {
        int s = 0;
#pragma unroll
        for (int h = 0; h < NHIST; ++h) s += cntP[h * 128 + t];
        cntA[t] = (float)s;
    }
    __syncthreads();
    const int li = labels[row];
    float S2 = supS[row], N2 = 0.f;
#pragma unroll 4
    for (int c = 0; c < NCG2; ++c) {
        S2 += pS[(size_t)c * BB + row];
        N2 += pN[(size_t)c * BB + row];
    }
    float S1 = 0.f, N1v = 0.f;
#pragma unroll
    for (int c = NCG2; c < NSL; ++c) {
        S1 += pS[(size_t)c * BB + row];
        N1v += pN[(size_t)c * BB + row];
    }
    N2 *= INV_T; N1v *= INV_T;
    float sli = supLi[row];
    float cA = cntA[li];
    float msum2 = fmaf(ALPHA, cA - 1.f, 1.f);
    float loss2 = -(fmaf(ALPHA, N2, sli) / msum2 - INV_T - logf(S2 + EPSV));
    float loss1 = -(N1v / (float)cntB[li] - INV_T - logf(S1 + EPSV));
    float s = (loss1 + loss2) * (1.0f / (float)BB);
    __shared__ float buf[2];
#pragma unroll
    for (int off = 1; off < 64; off <<= 1) s += __shfl_xor(s, off, 64);
    if ((t & 63) == 0) buf[t >> 6] = s;
    __syncthreads();
    if (t == 0) atomicAdd(out, buf[0] + buf[1]);   // out zeroed ONLY by host-side memset
}

extern "C" void kernel_launch(void* const* d_in, const int* in_sizes, int n_in,
                              void* d_out, int out_size, void* d_ws, size_t ws_size,
                              hipStream_t stream) {
    const float* feats   = (const float*)d_in[0];
    const float* sup     = (const float*)d_in[1];
    const float* centers = (const float*)d_in[2];
    const int*   labels  = (const int*)d_in[3];
    float* out = (float*)d_out;
    char*  wsb = (char*)d_ws;

    const size_t X2_BYTES = (size_t)NCB * 8192;         // 8,683,520
    unsigned short* X2 = (unsigned short*)wsb;
    char* base2 = wsb + X2_BYTES;
    int* cntP = (int*)base2;                            // 33*128 ints
    int* cntB = cntP + NHIST * 128;                     // 128 ints
    float* pS = (float*)(cntB + 128);                   // 141*1024
    float* pN = pS + (size_t)NSL * BB;                  // 141*1024
    float* supS  = pN + (size_t)NSL * BB;               // 1024
    float* supLi = supS + BB;                           // 1024

    hipMemsetAsync(out, 0, sizeof(float), stream);      // loss accumulator
    prep_k<<<NPB + NHIST, 256, 0, stream>>>(feats, centers, labels, X2, cntP, cntB);
    gemm_k<<<8 * 8 * 18, 256, 0, stream>>>(X2, labels, cntP, cntB, sup,
                                           pS, pN, supS, supLi);
    finalize_k<<<8, 128, 0, stream>>>(labels, cntP, cntB, pS, pN, supS, supLi, out);
}

// Round 16
// 129.620 us; speedup vs baseline: 2.0609x; 1.0514x over previous
//
#include <hip/hip_runtime.h>
#include <math.h>

#define KQ   32768
#define CC   100
#define BB   1024
#define DD   128
#define NTOT (BB + KQ)        // 33792
#define CB_CENT 1056
#define NCB  1060             // 32-row blocks in X2
#define NPB  265              // prep blocks (4 cb each)
#define NHIST 33              // histogram partial blocks
#define NCG2 66               // branch-2 col groups (16 cb each)
#define CG_SUP 75             // sup group id (after 9 branch-1 groups)
#define NSL  75               // partial-sum slices (66 b2 + 9 b1)

#define INV_T  14.285714285714286f
#define K2E    20.609929f     // INV_T * log2(e)
#define ALPHA  0.05f
#define EPSV   1e-12f

typedef __attribute__((ext_vector_type(8)))  short          short8;
typedef __attribute__((ext_vector_type(8)))  unsigned short ushort8;
typedef __attribute__((ext_vector_type(16))) float          float16;

__device__ __forceinline__ unsigned short f2bf_rne(float f) {
    unsigned int u = __float_as_uint(f);
    return (unsigned short)((u + 0x7FFFu + ((u >> 16) & 1u)) >> 16);
}

// X2 layout per 32-row block cb (8192 B): [ks 0..7][lane 0..63][16 B]
// element (row r, k): cb=r>>5, ks=k>>4, lane=(r&31)+32*((k>>3)&1), j=k&7
// == 32x32x16 MFMA A/B operand layout (verified R2-R15).
// HARD RULES: no device-scope fences/tickets in hot kernel (R13);
// never plain-store into a cross-block atomic accumulation target (R14).

// ---------------- prep: convert+tile (4 cb/block) + partial histograms ----------------
__global__ __launch_bounds__(256) void prep_k(const float* __restrict__ feats,
                                              const float* __restrict__ centers,
                                              const int* __restrict__ labels,
                                              unsigned short* __restrict__ X2,
                                              int* __restrict__ cntP,
                                              int* __restrict__ cntB) {
    const int b = blockIdx.x, t = threadIdx.x;
    if (b >= NPB) {  // histogram partials: each block owns its own 128-int slice
        const int h = b - NPB;
        __shared__ int hA[CC], hB[CC];
        if (t < CC) { hA[t] = 0; hB[t] = 0; }
        __syncthreads();
        const int base = h * 1024;
#pragma unroll
        for (int q = 0; q < 4; ++q) {
            int l = labels[base + q * 256 + t];
            atomicAdd(&hA[l], 1);
            if (h == 0) atomicAdd(&hB[l], 1);   // batch rows are exactly block 0's range
        }
        __syncthreads();
        if (t < 128) {
            cntP[h * 128 + t] = (t < CC) ? hA[t] : 0;
            if (h == 0) cntB[t] = (t < CC) ? hB[t] : 0;
        }
        return;
    }
    __shared__ unsigned short sm[8 * 66 * 8];   // stride-66 slots, reused per cb
    const int rl = t >> 3, c8 = t & 7;
#pragma unroll
    for (int cbi = 0; cbi < 4; ++cbi) {
        const int cb = b * 4 + cbi;
        if (cb >= NCB) break;
        const int r = cb * 32 + rl;
        const float* src;
        if (r < NTOT)            src = &feats[(size_t)r * DD];
        else if (r < NTOT + CC)  src = &centers[(size_t)(r - NTOT) * DD];
        else                     src = nullptr;
        if (cbi) __syncthreads();
#pragma unroll
        for (int s = 0; s < 2; ++s) {
            const int c8p = c8 + 8 * s;
            float v[8];
            if (src) {
                const float4* p = (const float4*)(src + c8p * 8);
                float4 q0 = p[0], q1 = p[1];
                v[0]=q0.x; v[1]=q0.y; v[2]=q0.z; v[3]=q0.w;
                v[4]=q1.x; v[5]=q1.y; v[6]=q1.z; v[7]=q1.w;
            } else {
#pragma unroll
                for (int j = 0; j < 8; ++j) v[j] = 0.f;
            }
            ushort8 H;
#pragma unroll
            for (int m = 0; m < 8; ++m) H[m] = f2bf_rne(v[m]);
            const int ks = c8p >> 1, lh = c8p & 1;
            *(ushort8*)&sm[(ks * 66 + rl + 32 * lh) * 8] = H;
        }
        __syncthreads();
        ushort8* dst = (ushort8*)((char*)X2 + (size_t)cb * 8192);
#pragma unroll
        for (int j = 0; j < 2; ++j) {
            const int idx = j * 256 + t;
            const int ks = idx >> 6, ln = idx & 63;
            dst[idx] = *(const ushort8*)&sm[(ks * 66 + ln) * 8];
        }
    }
}

// ---------------- epilogue for one 32x32 tile ----------------
__device__ __forceinline__ void epi_tile(
    const float16& acc, int cb, int lc, float rn, float drm, bool checkDiag,
    int half, int ln, int growbase, const int* rlab, float* sS, float* sN)
{
    const int ccol = cb * 32 + ln;
#pragma unroll
    for (int reg = 0; reg < 16; ++reg) {
        int ro = (reg & 3) + 8 * (reg >> 2) + 4 * half;
        float a  = acc[reg];
        float mf = (lc == rlab[reg]) ? 1.f : 0.f;
        float wgt = fmaf(mf, drm, rn);
        if (checkDiag) {                 // wave-uniform
            bool d = (ccol == growbase + ro);
            wgt = d ? 0.f : wgt;
            mf  = d ? 0.f : mf;
        }
        float e = exp2f(fmaf(a, K2E, -K2E));
        sS[reg] = fmaf(e, wgt, sS[reg]);
        sN[reg] = fmaf(mf, a, sN[reg]);  // un-scaled dot; *INV_T at finalize
    }
}

// ---------------- dual-stream pair of 32x32 tiles ----------------
__device__ __forceinline__ void pair_tiles(
    const char* Xb, int cb0, int cb1,
    int lc0, float rn0, float drm0, bool dg0,
    int lc1, float rn1, float drm1, bool dg1,
    int lane, int half, int ln, int growbase,
    const short8* Ah, const int* rlab, float* sS, float* sN)
{
    const size_t b0 = (size_t)cb0 * 8192 + (size_t)lane * 16;
    const size_t b1 = (size_t)cb1 * 8192 + (size_t)lane * 16;
    float16 a0, a1;
#pragma unroll
    for (int reg = 0; reg < 16; ++reg) { a0[reg] = 0.f; a1[reg] = 0.f; }
#pragma unroll
    for (int ks = 0; ks < 8; ++ks) {
        short8 B0 = *(const short8*)(Xb + b0 + (size_t)ks * 1024);
        short8 B1 = *(const short8*)(Xb + b1 + (size_t)ks * 1024);
        a0 = __builtin_amdgcn_mfma_f32_32x32x16_bf16(Ah[ks], B0, a0, 0, 0, 0);
        a1 = __builtin_amdgcn_mfma_f32_32x32x16_bf16(Ah[ks], B1, a1, 0, 0, 0);
    }
    epi_tile(a0, cb0, lc0, rn0, drm0, dg0, half, ln, growbase, rlab, sS, sN);
    epi_tile(a1, cb1, lc1, rn1, drm1, dg1, half, ln, growbase, rlab, sS, sN);
}

// ---------------- fused GEMM (b2 + b1) + sup-sums; LDS weight table; store epilogue ----------
// grid 640 = 8 xcd * 8 rt * 10 ci; cg = xcd + 8*ci.
// cg<66: branch2 (16 cb). 66..74: branch1 (4 cb). 75: sup sums. >75: idle.
__global__ __launch_bounds__(256) void gemm_k(
    const unsigned short* __restrict__ X2, const int* __restrict__ labels,
    const int* __restrict__ cntP, const int* __restrict__ cntB,
    const float* __restrict__ sup,
    float* __restrict__ pS, float* __restrict__ pN,
    float* __restrict__ supS, float* __restrict__ supLi) {
    const int b = blockIdx.x;
    const int xcd = b & 7, l = b >> 3;
    const int rt = l & 7, ci = l >> 3;
    const int cg = xcd + 8 * ci;
    if (cg > CG_SUP) return;

    const int tid = threadIdx.x;
    const int lane = tid & 63, w = tid >> 6;
    const int half = lane >> 5, ln = lane & 31;
    const char* Xb = (const char*)X2;

    // block-local weight tables from histogram partials (no cross-block ordering)
    __shared__ float cntAF[128], rnA[128], drmA[128], rn1S[128], drm1S[128];
    if (tid < 128) {
        int s = 0;
#pragma unroll
        for (int h = 0; h < NHIST; ++h) s += cntP[h * 128 + tid];
        float cf = (float)s;
        cntAF[tid] = cf;
        rnA[tid] = (s > 0) ? __builtin_amdgcn_rcpf(cf) : 0.f;
        drmA[tid] = (s > 0) ? (__builtin_amdgcn_rcpf(cf - ALPHA) - rnA[tid]) : 0.f;
        int sb = cntB[tid];
        float c1 = (float)(sb + 1);
        float rn1 = __builtin_amdgcn_rcpf(c1);
        rn1S[tid] = rn1;
        drm1S[tid] = __builtin_amdgcn_rcpf(fmaxf(c1 - 1.f, 1.f)) - rn1;
    }
    __syncthreads();

    if (cg == CG_SUP) {  // sup-logits exp-sums, coalesced (lane = class), wave = 32 rows
        const int g = rt * 4 + w;
        const int c0 = lane, c1 = lane + 64;
        float n0 = cntAF[c0];
        float rA0 = __builtin_amdgcn_rcpf(n0);
        float rAm0 = __builtin_amdgcn_rcpf(fmaxf(n0 - 1.f, 1.f));
        float rA1 = 0.f, rAm1 = 0.f;
        if (lane < 36) {
            float n1 = cntAF[c1];
            rA1 = __builtin_amdgcn_rcpf(n1);
            rAm1 = __builtin_amdgcn_rcpf(fmaxf(n1 - 1.f, 1.f));
        }
        for (int rr = 0; rr < 32; ++rr) {
            int row = g * 32 + rr;
            int li = labels[row];
            const float* srow = &sup[(size_t)row * CC];
            float v0 = srow[c0];
            float s = __expf(v0 - INV_T) * ((c0 == li) ? rAm0 : rA0);
            float liv = (c0 == li) ? v0 : 0.f;
            if (lane < 36) {
                float v1 = srow[c1];
                s += __expf(v1 - INV_T) * ((c1 == li) ? rAm1 : rA1);
                liv += (c1 == li) ? v1 : 0.f;
            }
#pragma unroll
            for (int off = 1; off < 64; off <<= 1) {
                s += __shfl_xor(s, off, 64);
                liv += __shfl_xor(liv, off, 64);
            }
            if (lane == 0) { supS[row] = s; supLi[row] = liv; }
        }
        return;
    }

    const int rb = rt * 4 + w;
    const int growbase = rt * 128 + w * 32;
    short8 Ah[8];
    {
        size_t abase = (size_t)rb * 8192 + (size_t)lane * 16;
#pragma unroll
        for (int ks = 0; ks < 8; ++ks)
            Ah[ks] = *(const short8*)(Xb + abase + (size_t)ks * 1024);
    }
    int rlab[16];
#pragma unroll
    for (int reg = 0; reg < 16; ++reg) {
        int ro = (reg & 3) + 8 * (reg >> 2) + 4 * half;
        rlab[reg] = labels[growbase + ro];
    }
    float sS[16], sN[16];
#pragma unroll
    for (int reg = 0; reg < 16; ++reg) { sS[reg] = 0.f; sN[reg] = 0.f; }

    const bool isB2 = (cg < NCG2);
    const int t1 = cg - NCG2;
    if (isB2) {
#pragma unroll
        for (int p = 0; p < 8; ++p) {
            const int cb0 = cg * 16 + 2 * p, cb1 = cb0 + 1;
            int lc0 = labels[cb0 * 32 + ln];
            int lc1 = labels[cb1 * 32 + ln];
            pair_tiles(Xb, cb0, cb1, lc0, rnA[lc0], drmA[lc0], cb0 == rb,
                       lc1, rnA[lc1], drmA[lc1], cb1 == rb,
                       lane, half, ln, growbase, Ah, rlab, sS, sN);
        }
    } else {
        const bool isBatch = (t1 < 8);
#pragma unroll
        for (int p = 0; p < 2; ++p) {
            int cb0, cb1, lc0, lc1;
            if (isBatch) {
                cb0 = t1 * 4 + 2 * p; cb1 = cb0 + 1;
                lc0 = labels[cb0 * 32 + ln];
                lc1 = labels[cb1 * 32 + ln];
            } else {
                cb0 = CB_CENT + 2 * p; cb1 = cb0 + 1;
                int q0 = cb0 * 32 + ln - NTOT, q1 = cb1 * 32 + ln - NTOT;
                lc0 = (q0 < CC) ? q0 : -1;
                lc1 = (q1 < CC) ? q1 : -1;
            }
            float rn0 = (lc0 >= 0) ? rn1S[lc0] : 0.f;
            float drm0 = (lc0 >= 0) ? drm1S[lc0] : 0.f;
            float rn1 = (lc1 >= 0) ? rn1S[lc1] : 0.f;
            float drm1 = (lc1 >= 0) ? drm1S[lc1] : 0.f;
            pair_tiles(Xb, cb0, cb1, lc0, rn0, drm0, isBatch && (cb0 == rb),
                       lc1, rn1, drm1, isBatch && (cb1 == rb),
                       lane, half, ln, growbase, Ah, rlab, sS, sN);
        }
    }
    const int slice = isB2 ? cg : (NCG2 + t1);
#pragma unroll
    for (int reg = 0; reg < 16; ++reg) {
        float a = sS[reg], c = sN[reg];
#pragma unroll
        for (int off = 1; off < 32; off <<= 1) {
            a += __shfl_xor(a, off, 64);
            c += __shfl_xor(c, off, 64);
        }
        if (ln == 0) {
            int ro = (reg & 3) + 8 * (reg >> 2) + 4 * half;
            int grow = growbase + ro;
            pS[(size_t)slice * BB + grow] = a;
            pN[(size_t)slice * BB + grow] = c;
        }
    }
}

// ---------------- finalize: one block, 1024 threads, plain store (no memset needed) --------
__global__ __launch_bounds__(1024) void finalize_k(
    const int* __restrict__ labels,
    const int* __restrict__ cntP, const int* __restrict__ cntB,
    const float* __restrict__ pS, const float* __restrict__ pN,
    const float* __restrict__ supS, const float* __restrict__ supLi,
    float* __restrict__ out) {
    const int t = threadIdx.x;
    __shared__ float cntA[128];
    if (t < 128) {
        int s = 0;
#pragma unroll
        for (int h = 0; h < NHIST; ++h) s += cntP[h * 128 + t];
        cntA[t] = (float)s;
    }
    __syncthreads();
    const int li = labels[t];
    float S2 = supS[t], N2 = 0.f;
#pragma unroll 4
    for (int c = 0; c < NCG2; ++c) {
        S2 += pS[(size_t)c * BB + t];
        N2 += pN[(size_t)c * BB + t];
    }
    float S1 = 0.f, N1v = 0.f;
#pragma unroll
    for (int c = NCG2; c < NSL; ++c) {
        S1 += pS[(size_t)c * BB + t];
        N1v += pN[(size_t)c * BB + t];
    }
    N2 *= INV_T; N1v *= INV_T;
    float sli = supLi[t];
    float cA = cntA[li];
    float msum2 = fmaf(ALPHA, cA - 1.f, 1.f);
    float loss2 = -(fmaf(ALPHA, N2, sli) / msum2 - INV_T - logf(S2 + EPSV));
    float loss1 = -(N1v / (float)cntB[li] - INV_T - logf(S1 + EPSV));
    float s = loss1 + loss2;
    __shared__ float buf[16];
#pragma unroll
    for (int off = 1; off < 64; off <<= 1) s += __shfl_xor(s, off, 64);
    if ((t & 63) == 0) buf[t >> 6] = s;
    __syncthreads();
    if (t < 64) {
        float x = (t < 16) ? buf[t] : 0.f;
#pragma unroll
        for (int off = 1; off < 16; off <<= 1) x += __shfl_xor(x, off, 64);
        if (t == 0) out[0] = x / (float)BB;   // single writer, plain store
    }
}

extern "C" void kernel_launch(void* const* d_in, const int* in_sizes, int n_in,
                              void* d_out, int out_size, void* d_ws, size_t ws_size,
                              hipStream_t stream) {
    const float* feats   = (const float*)d_in[0];
    const float* sup     = (const float*)d_in[1];
    const float* centers = (const float*)d_in[2];
    const int*   labels  = (const int*)d_in[3];
    float* out = (float*)d_out;
    char*  wsb = (char*)d_ws;

    const size_t X2_BYTES = (size_t)NCB * 8192;         // 8,683,520
    unsigned short* X2 = (unsigned short*)wsb;
    char* base2 = wsb + X2_BYTES;
    int* cntP = (int*)base2;                            // 33*128 ints
    int* cntB = cntP + NHIST * 128;                     // 128 ints
    float* pS = (float*)(cntB + 128);                   // 75*1024
    float* pN = pS + (size_t)NSL * BB;                  // 75*1024
    float* supS  = pN + (size_t)NSL * BB;               // 1024
    float* supLi = supS + BB;                           // 1024

    // 3 nodes; every workspace word written before read
    prep_k<<<NPB + NHIST, 256, 0, stream>>>(feats, centers, labels, X2, cntP, cntB);
    gemm_k<<<8 * 8 * 10, 256, 0, stream>>>(X2, labels, cntP, cntB, sup,
                                           pS, pN, supS, supLi);
    finalize_k<<<1, 1024, 0, stream>>>(labels, cntP, cntB, pS, pN, supS, supLi, out);
}